// Round 9
// baseline (270.310 us; speedup 1.0000x reference)
//
#include <hip/hip_runtime.h>

#define IN_H 200
#define IN_W 200
#define NCH  256
#define NROI 512
#define OUT_HW 49
#define PLANE (IN_H * IN_W)
#define NTILE_B 625        // 64-px tiles per batch
#define NGRP 25            // row-groups per batch (8 rows each = 1600 px = 25 tiles)
#define TILES_PER_GRP 25

__device__ inline void acc8(float* acc, uint4 q, float w) {
  acc[0] += w * __uint_as_float(q.x << 16);
  acc[1] += w * __uint_as_float(q.x & 0xffff0000u);
  acc[2] += w * __uint_as_float(q.y << 16);
  acc[3] += w * __uint_as_float(q.y & 0xffff0000u);
  acc[4] += w * __uint_as_float(q.z << 16);
  acc[5] += w * __uint_as_float(q.z & 0xffff0000u);
  acc[6] += w * __uint_as_float(q.w << 16);
  acc[7] += w * __uint_as_float(q.w & 0xffff0000u);
}

// Fused producer-consumer: all 1250 blocks transpose one tile; blocks <1024
// then each compute half a roi, spin-waiting on the row-group flags they need.
// Co-residency guaranteed: LDS 25088B -> 6 blocks/CU -> 1536 slots >= 1250.
__global__ __launch_bounds__(256, 6) void fused_kernel(
    const float* __restrict__ in,
    const float* __restrict__ rois,
    ushort* __restrict__ nhwc,
    int* __restrict__ cnt,
    float* __restrict__ out) {
  __shared__ union {
    ushort tbuf[64][132];          // 16896 B (pad 132: 2-way banks, 8B rows)
    float  sout[128 * OUT_HW];     // 25088 B
  } sh;

  const int bid = blockIdx.x;
  const int t   = threadIdx.x;

  // ---------------- producer phase: transpose tile `bid` ----------------
  {
    const int bb  = bid / NTILE_B;
    const int hwt = bid % NTILE_B;
    const int hw0 = hwt * 64;
    const int w = t >> 6, l = t & 63;
    const float* src = in + (size_t)bb * NCH * PLANE + hw0;
    ushort* dst = nhwc + ((size_t)bb * PLANE + hw0) * NCH;
#pragma unroll
    for (int ch0 = 0; ch0 < NCH; ch0 += 128) {
      __syncthreads();             // guard tbuf reuse across passes
#pragma unroll 4
      for (int i = 0; i < 32; ++i) {
        const int c = ch0 + w * 32 + i;
        const float v = src[(size_t)c * PLANE + l];
        const unsigned u = __float_as_uint(v);
        const unsigned rr = (u + 0x7fffu + ((u >> 16) & 1u)) >> 16;  // RN-even
        sh.tbuf[l][c - ch0] = (ushort)rr;
      }
      __syncthreads();
      for (int m = t; m < 64 * 32; m += 256) {
        const int h = m >> 5;
        const int q = m & 31;
        *(ushort4*)(dst + (size_t)h * NCH + ch0 + q * 4) =
            *(const ushort4*)&sh.tbuf[h][q * 4];
      }
    }
    __threadfence();               // each thread makes its stores agent-visible
    __syncthreads();
    if (t == 0) {
      __hip_atomic_fetch_add(&cnt[bb * NGRP + hwt / TILES_PER_GRP], 1,
                             __ATOMIC_RELEASE, __HIP_MEMORY_SCOPE_AGENT);
    }
  }

  if (bid >= NROI * 2) return;

  // ---------------- consumer phase: half a roi (128 channels) ----------------
  const int k    = bid >> 1;
  const int half = bid & 1;
  const int pg   = t >> 4;             // 0..15
  const int cl   = (t & 15) * 8;       // local channel 0..120
  const int c0   = half * 128 + cl;

  const float* r = rois + k * 5;
  const int   rb  = (int)r[0];
  const float x1s = r[1] * 0.25f;
  const float y1s = r[2] * 0.25f;
  const float x2s = r[3] * 0.25f;
  const float y2s = r[4] * 0.25f;
  const float roi_w = fmaxf(x2s - x1s, 1.0f);
  const float roi_h = fmaxf(y2s - y1s, 1.0f);
  const float bw = roi_w / 7.0f;
  const float bh = roi_h / 7.0f;

  const float ymin_s = y1s + 0.25f * bh;
  const float ymax_s = y1s + 6.75f * bh;
  const bool valid = (ymin_s >= -1.0f) && (ymax_s <= (float)IN_H) &&
                     (x1s + 0.25f * bw >= -1.0f) && (x1s + 6.75f * bw <= (float)IN_W);
  const float scale = valid ? 0.25f : 0.0f;

  // rows this roi touches -> row-groups to wait on
  {
    const int ylo = (int)floorf(fminf(fmaxf(ymin_s, 0.0f), (float)(IN_H - 1)));
    const int yhi = min((int)floorf(fminf(fmaxf(ymax_s, 0.0f), (float)(IN_H - 1))) + 1,
                        IN_H - 1);
    const int g0 = rb * NGRP + (ylo >> 3);
    const int g1 = rb * NGRP + (yhi >> 3);
    if (t == 0) {
      for (int g = g0; g <= g1; ++g) {
        int iters = 0;
        while (__hip_atomic_load(&cnt[g], __ATOMIC_ACQUIRE,
                                 __HIP_MEMORY_SCOPE_AGENT) < TILES_PER_GRP) {
          __builtin_amdgcn_s_sleep(2);
          if (++iters > (1 << 22)) break;   // watchdog, never expected
        }
      }
    }
    __syncthreads();   // all lanes see completed groups; also guards sh union reuse
  }

  const ushort* base = nhwc + (size_t)rb * PLANE * NCH + c0;

  for (int p = pg; p < OUT_HW; p += 16) {
    const int ph = p / 7;
    const int pw = p - ph * 7;
    const float ybase = y1s + bh * (float)ph;
    const float xbase = x1s + bw * (float)pw;

    float acc[8] = {0.f, 0.f, 0.f, 0.f, 0.f, 0.f, 0.f, 0.f};
#pragma unroll
    for (int iy = 0; iy < 2; ++iy) {
      const float y  = ybase + (bh * 0.5f) * ((float)iy + 0.5f);
      const float yc = fminf(fmaxf(y, 0.0f), (float)(IN_H - 1));
      const float ylf = floorf(yc);
      const int   yl  = (int)ylf;
      const int   yh  = min(yl + 1, IN_H - 1);
      const float ly  = yc - ylf;
      const float hy  = 1.0f - ly;
      const ushort* rowl = base + (size_t)yl * IN_W * NCH;
      const ushort* rowh = base + (size_t)yh * IN_W * NCH;
#pragma unroll
      for (int ix = 0; ix < 2; ++ix) {
        const float x  = xbase + (bw * 0.5f) * ((float)ix + 0.5f);
        const float xc = fminf(fmaxf(x, 0.0f), (float)(IN_W - 1));
        const float xlf = floorf(xc);
        const int   xl  = (int)xlf;
        const int   xh  = min(xl + 1, IN_W - 1);
        const float lx  = xc - xlf;
        const float hx  = 1.0f - lx;

        const uint4 q1 = *(const uint4*)(rowl + (size_t)xl * NCH);
        const uint4 q2 = *(const uint4*)(rowl + (size_t)xh * NCH);
        const uint4 q3 = *(const uint4*)(rowh + (size_t)xl * NCH);
        const uint4 q4 = *(const uint4*)(rowh + (size_t)xh * NCH);

        acc8(acc, q1, hy * hx);
        acc8(acc, q2, hy * lx);
        acc8(acc, q3, ly * hx);
        acc8(acc, q4, ly * lx);
      }
    }
#pragma unroll
    for (int j = 0; j < 8; ++j) sh.sout[(cl + j) * OUT_HW + p] = acc[j] * scale;
  }
  __syncthreads();

  float4* o4 = (float4*)(out + ((size_t)k * NCH + half * 128) * OUT_HW);
  const float4* s4 = (const float4*)sh.sout;
  for (int m = t; m < (128 * OUT_HW) / 4; m += 256) o4[m] = s4[m];
}

// ---------------- fallback (ws too small): direct gather, f32 NCHW ----------------
__global__ __launch_bounds__(256) void roi_align_fallback(
    const float* __restrict__ input,
    const float* __restrict__ rois,
    float* __restrict__ out) {
  const int blk  = blockIdx.x;
  const int k    = blk >> 6;
  const int cg   = blk & 63;
  const int wave = threadIdx.x >> 6;
  const int lane = threadIdx.x & 63;
  const int c    = (cg << 2) + wave;

  const float* r = rois + k * 5;
  const int   b   = (int)r[0];
  const float x1s = r[1] * 0.25f;
  const float y1s = r[2] * 0.25f;
  const float roi_w = fmaxf(r[3] * 0.25f - x1s, 1.0f);
  const float roi_h = fmaxf(r[4] * 0.25f - y1s, 1.0f);
  const float bw = roi_w / 7.0f;
  const float bh = roi_h / 7.0f;
  const bool valid = (y1s + 0.25f * bh >= -1.0f) && (y1s + 6.75f * bh <= (float)IN_H) &&
                     (x1s + 0.25f * bw >= -1.0f) && (x1s + 6.75f * bw <= (float)IN_W);
  if (lane >= OUT_HW) return;
  const int ph = lane / 7;
  const int pw = lane - ph * 7;
  const float* plane = input + ((size_t)(b * NCH + c)) * PLANE;
  const float ybase = y1s + bh * (float)ph;
  const float xbase = x1s + bw * (float)pw;
  float acc = 0.0f;
#pragma unroll
  for (int iy = 0; iy < 2; ++iy) {
    const float y  = ybase + (bh * 0.5f) * ((float)iy + 0.5f);
    const float yc = fminf(fmaxf(y, 0.0f), (float)(IN_H - 1));
    const float ylf = floorf(yc);
    const int yl = (int)ylf;
    const int yh = min(yl + 1, IN_H - 1);
    const float ly = yc - ylf, hy = 1.0f - ly;
#pragma unroll
    for (int ix = 0; ix < 2; ++ix) {
      const float x  = xbase + (bw * 0.5f) * ((float)ix + 0.5f);
      const float xc = fminf(fmaxf(x, 0.0f), (float)(IN_W - 1));
      const float xlf = floorf(xc);
      const int xl = (int)xlf;
      const int xh = min(xl + 1, IN_W - 1);
      const float lx = xc - xlf, hx = 1.0f - lx;
      const float* row_l = plane + yl * IN_W;
      const float* row_h = plane + yh * IN_W;
      acc += hy * hx * row_l[xl] + hy * lx * row_l[xh] +
             ly * hx * row_h[xl] + ly * lx * row_h[xh];
    }
  }
  out[((size_t)k * NCH + c) * OUT_HW + lane] = valid ? acc * 0.25f : 0.0f;
}

extern "C" void kernel_launch(void* const* d_in, const int* in_sizes, int n_in,
                              void* d_out, int out_size, void* d_ws, size_t ws_size,
                              hipStream_t stream) {
  const float* input = (const float*)d_in[0];
  const float* rois  = (const float*)d_in[1];
  float* out = (float*)d_out;

  const size_t nhwc_bytes = (size_t)2 * PLANE * NCH * sizeof(ushort);  // 40.96 MB
  const size_t need = nhwc_bytes + 64 * sizeof(int);
  if (ws_size >= need) {
    ushort* nhwc = (ushort*)d_ws;
    int* cnt = (int*)((char*)d_ws + nhwc_bytes);
    hipMemsetAsync(cnt, 0, 64 * sizeof(int), stream);   // graph-capturable
    fused_kernel<<<2 * NTILE_B, 256, 0, stream>>>(input, rois, nhwc, cnt, out);
  } else {
    roi_align_fallback<<<NROI * (NCH / 4), 256, 0, stream>>>(input, rois, out);
  }
}

// Round 10
// 52.869 us; speedup vs baseline: 5.1128x; 5.1128x over previous
//
#include <hip/hip_runtime.h>

#define IN_H 200
#define IN_W 200
#define NCH  256
#define NROI 512
#define OUT_HW 49
#define PLANE (IN_H * IN_W)
#define NTILE_B 625        // 64-px tiles per batch image

__device__ inline void acc8(float* acc, uint4 q, float w) {
  acc[0] += w * __uint_as_float(q.x << 16);
  acc[1] += w * __uint_as_float(q.x & 0xffff0000u);
  acc[2] += w * __uint_as_float(q.y << 16);
  acc[3] += w * __uint_as_float(q.y & 0xffff0000u);
  acc[4] += w * __uint_as_float(q.z << 16);
  acc[5] += w * __uint_as_float(q.z & 0xffff0000u);
  acc[6] += w * __uint_as_float(q.w << 16);
  acc[7] += w * __uint_as_float(q.w & 0xffff0000u);
}

union ShMem {
  ushort t[64][260];           // transpose tile: 33280 B
  float  sout[128 * OUT_HW];   // roi output tile: 25088 B
};

// PHASE 0: transpose batch 0 (grid 625)
// PHASE 1: bid<625 -> transpose batch 1; else roi slot (b==0 only) (grid 1649)
// PHASE 2: roi slot (b==1 only) (grid 1024)
template <int PHASE>
__global__ __launch_bounds__(256) void stage_kernel(
    const float* __restrict__ in,
    const float* __restrict__ rois,
    ushort* __restrict__ nhwc,
    float* __restrict__ out) {
  __shared__ ShMem sh;
  const int bid = blockIdx.x;
  const int tid = threadIdx.x;

  // ---------------- transpose path ----------------
  if (PHASE == 0 || (PHASE == 1 && bid < NTILE_B)) {
    const int tb  = (PHASE == 0) ? 0 : 1;
    const int hwt = bid;
    const int hw0 = hwt * 64;
    const int w = tid >> 6, l = tid & 63;

    const float* src = in + (size_t)tb * NCH * PLANE + hw0;
#pragma unroll 4
    for (int i = 0; i < 64; ++i) {
      const int c = w * 64 + i;
      const float v = src[(size_t)c * PLANE + l];
      const unsigned u = __float_as_uint(v);
      const unsigned rr = (u + 0x7fffu + ((u >> 16) & 1u)) >> 16;  // RN-even
      sh.t[l][c] = (ushort)rr;
    }
    __syncthreads();
    ushort* dst = nhwc + ((size_t)tb * PLANE + hw0) * NCH;
    for (int m = tid; m < 64 * 64; m += 256) {
      const int h = m >> 6;
      const int q = m & 63;
      *(ushort4*)(dst + (size_t)h * NCH + q * 4) = *(const ushort4*)&sh.t[h][q * 4];
    }
    return;
  }

  // ---------------- roi path (half a roi = 128 channels) ----------------
  const int slot = (PHASE == 1) ? (bid - NTILE_B) : bid;
  const int k    = slot >> 1;
  const int half = slot & 1;

  const float* r = rois + k * 5;
  const int rb = (int)r[0];
  if (PHASE == 1) { if (rb != 0) return; }
  else            { if (rb != 1) return; }

  const int pg = tid >> 4;             // 0..15
  const int cl = (tid & 15) * 8;       // local channel 0..120
  const int c0 = half * 128 + cl;

  const float x1s = r[1] * 0.25f;
  const float y1s = r[2] * 0.25f;
  const float x2s = r[3] * 0.25f;
  const float y2s = r[4] * 0.25f;
  const float roi_w = fmaxf(x2s - x1s, 1.0f);
  const float roi_h = fmaxf(y2s - y1s, 1.0f);
  const float bw = roi_w / 7.0f;
  const float bh = roi_h / 7.0f;

  // whole-roi validity (coords monotone: min at p=0,i=0; max at p=6,i=1)
  const bool valid = (y1s + 0.25f * bh >= -1.0f) && (y1s + 6.75f * bh <= (float)IN_H) &&
                     (x1s + 0.25f * bw >= -1.0f) && (x1s + 6.75f * bw <= (float)IN_W);
  const float scale = valid ? 0.25f : 0.0f;

  const ushort* base = nhwc + (size_t)rb * PLANE * NCH + c0;

  for (int p = pg; p < OUT_HW; p += 16) {
    const int ph = p / 7;
    const int pw = p - ph * 7;
    const float ybase = y1s + bh * (float)ph;
    const float xbase = x1s + bw * (float)pw;

    float acc[8] = {0.f, 0.f, 0.f, 0.f, 0.f, 0.f, 0.f, 0.f};
#pragma unroll
    for (int iy = 0; iy < 2; ++iy) {
      const float y  = ybase + (bh * 0.5f) * ((float)iy + 0.5f);
      const float yc = fminf(fmaxf(y, 0.0f), (float)(IN_H - 1));
      const float ylf = floorf(yc);
      const int   yl  = (int)ylf;
      const int   yh  = min(yl + 1, IN_H - 1);
      const float ly  = yc - ylf;
      const float hy  = 1.0f - ly;
      const ushort* rowl = base + (size_t)yl * IN_W * NCH;
      const ushort* rowh = base + (size_t)yh * IN_W * NCH;
#pragma unroll
      for (int ix = 0; ix < 2; ++ix) {
        const float x  = xbase + (bw * 0.5f) * ((float)ix + 0.5f);
        const float xc = fminf(fmaxf(x, 0.0f), (float)(IN_W - 1));
        const float xlf = floorf(xc);
        const int   xl  = (int)xlf;
        const int   xh  = min(xl + 1, IN_W - 1);
        const float lx  = xc - xlf;
        const float hx  = 1.0f - lx;

        const uint4 q1 = *(const uint4*)(rowl + (size_t)xl * NCH);
        const uint4 q2 = *(const uint4*)(rowl + (size_t)xh * NCH);
        const uint4 q3 = *(const uint4*)(rowh + (size_t)xl * NCH);
        const uint4 q4 = *(const uint4*)(rowh + (size_t)xh * NCH);

        acc8(acc, q1, hy * hx);
        acc8(acc, q2, hy * lx);
        acc8(acc, q3, ly * hx);
        acc8(acc, q4, ly * lx);
      }
    }
#pragma unroll
    for (int j = 0; j < 8; ++j) sh.sout[(cl + j) * OUT_HW + p] = acc[j] * scale;
  }
  __syncthreads();

  // contiguous coalesced write of this half-roi's (128,7,7) tile
  float4* o4 = (float4*)(out + ((size_t)k * NCH + half * 128) * OUT_HW);
  const float4* s4 = (const float4*)sh.sout;
  for (int m = tid; m < (128 * OUT_HW) / 4; m += 256) o4[m] = s4[m];
}

// ---------------- fallback (ws too small): direct gather, f32 NCHW ----------------
__global__ __launch_bounds__(256) void roi_align_fallback(
    const float* __restrict__ input,
    const float* __restrict__ rois,
    float* __restrict__ out) {
  const int blk  = blockIdx.x;
  const int k    = blk >> 6;
  const int cg   = blk & 63;
  const int wave = threadIdx.x >> 6;
  const int lane = threadIdx.x & 63;
  const int c    = (cg << 2) + wave;

  const float* r = rois + k * 5;
  const int   b   = (int)r[0];
  const float x1s = r[1] * 0.25f;
  const float y1s = r[2] * 0.25f;
  const float roi_w = fmaxf(r[3] * 0.25f - x1s, 1.0f);
  const float roi_h = fmaxf(r[4] * 0.25f - y1s, 1.0f);
  const float bw = roi_w / 7.0f;
  const float bh = roi_h / 7.0f;
  const bool valid = (y1s + 0.25f * bh >= -1.0f) && (y1s + 6.75f * bh <= (float)IN_H) &&
                     (x1s + 0.25f * bw >= -1.0f) && (x1s + 6.75f * bw <= (float)IN_W);
  if (lane >= OUT_HW) return;
  const int ph = lane / 7;
  const int pw = lane - ph * 7;
  const float* plane = input + ((size_t)(b * NCH + c)) * PLANE;
  const float ybase = y1s + bh * (float)ph;
  const float xbase = x1s + bw * (float)pw;
  float acc = 0.0f;
#pragma unroll
  for (int iy = 0; iy < 2; ++iy) {
    const float y  = ybase + (bh * 0.5f) * ((float)iy + 0.5f);
    const float yc = fminf(fmaxf(y, 0.0f), (float)(IN_H - 1));
    const float ylf = floorf(yc);
    const int yl = (int)ylf;
    const int yh = min(yl + 1, IN_H - 1);
    const float ly = yc - ylf, hy = 1.0f - ly;
#pragma unroll
    for (int ix = 0; ix < 2; ++ix) {
      const float x  = xbase + (bw * 0.5f) * ((float)ix + 0.5f);
      const float xc = fminf(fmaxf(x, 0.0f), (float)(IN_W - 1));
      const float xlf = floorf(xc);
      const int xl = (int)xlf;
      const int xh = min(xl + 1, IN_W - 1);
      const float lx = xc - xlf, hx = 1.0f - lx;
      const float* row_l = plane + yl * IN_W;
      const float* row_h = plane + yh * IN_W;
      acc += hy * hx * row_l[xl] + hy * lx * row_l[xh] +
             ly * hx * row_h[xl] + ly * lx * row_h[xh];
    }
  }
  out[((size_t)k * NCH + c) * OUT_HW + lane] = valid ? acc * 0.25f : 0.0f;
}

extern "C" void kernel_launch(void* const* d_in, const int* in_sizes, int n_in,
                              void* d_out, int out_size, void* d_ws, size_t ws_size,
                              hipStream_t stream) {
  const float* input = (const float*)d_in[0];
  const float* rois  = (const float*)d_in[1];
  float* out = (float*)d_out;

  const size_t need = (size_t)2 * PLANE * NCH * sizeof(ushort);  // 40.96 MB
  if (ws_size >= need) {
    ushort* nhwc = (ushort*)d_ws;
    stage_kernel<0><<<NTILE_B, 256, 0, stream>>>(input, rois, nhwc, out);
    stage_kernel<1><<<NTILE_B + 2 * NROI, 256, 0, stream>>>(input, rois, nhwc, out);
    stage_kernel<2><<<2 * NROI, 256, 0, stream>>>(input, rois, nhwc, out);
  } else {
    roi_align_fallback<<<NROI * (NCH / 4), 256, 0, stream>>>(input, rois, out);
  }
}

// Round 11
// 42.699 us; speedup vs baseline: 6.3306x; 1.2382x over previous
//
#include <hip/hip_runtime.h>

#define IN_H 200
#define IN_W 200
#define NCH  256
#define NROI 512
#define OUT_HW 49
#define PLANE (IN_H * IN_W)

// ---------------- kernel 1: NCHW f32 -> NHWC bf16 ----------------
__global__ __launch_bounds__(256) void transpose_bf16_kernel(
    const float* __restrict__ in, ushort* __restrict__ nhwc) {
  __shared__ ushort t[64][260];
  const int blk = blockIdx.x;
  const int hwt = blk % 625;
  const int b   = blk / 625;
  const int w = threadIdx.x >> 6, l = threadIdx.x & 63;
  const int hw0 = hwt * 64;

  const float* src = in + (size_t)b * NCH * PLANE + hw0;
#pragma unroll 4
  for (int i = 0; i < 64; ++i) {
    const int c = w * 64 + i;
    const float v = src[(size_t)c * PLANE + l];
    const unsigned u = __float_as_uint(v);
    const unsigned r = (u + 0x7fffu + ((u >> 16) & 1u)) >> 16;  // RN-even
    t[l][c] = (ushort)r;
  }
  __syncthreads();

  ushort* dst = nhwc + ((size_t)b * PLANE + hw0) * NCH;
#pragma unroll
  for (int m = threadIdx.x; m < 64 * 64; m += 256) {
    const int h = m >> 6;
    const int q = m & 63;
    *(ushort4*)(dst + (size_t)h * NCH + q * 4) = *(const ushort4*)&t[h][q * 4];
  }
}

__device__ inline void acc8(float* acc, uint4 q, float w) {
  acc[0] += w * __uint_as_float(q.x << 16);
  acc[1] += w * __uint_as_float(q.x & 0xffff0000u);
  acc[2] += w * __uint_as_float(q.y << 16);
  acc[3] += w * __uint_as_float(q.y & 0xffff0000u);
  acc[4] += w * __uint_as_float(q.z << 16);
  acc[5] += w * __uint_as_float(q.z & 0xffff0000u);
  acc[6] += w * __uint_as_float(q.w << 16);
  acc[7] += w * __uint_as_float(q.w & 0xffff0000u);
}

// ---------------- kernel 2: ROIAlign from bf16 NHWC ----------------
// block = quarter roi (64 ch); 256 thr; thread: 8 ch (uint4), pixel-groups of 32
__global__ __launch_bounds__(256) void roi_nhwc_bf16_kernel(
    const ushort* __restrict__ nhwc,
    const float* __restrict__ rois,
    float* __restrict__ out) {
  __shared__ float sout[64 * OUT_HW];  // 12544 B -> 8+ blocks/CU

  const int blk  = blockIdx.x;
  const int k    = blk >> 2;
  const int quad = blk & 3;
  const int t    = threadIdx.x;
  const int pg   = t >> 3;             // 0..31
  const int cl   = (t & 7) * 8;        // local channel 0..56
  const int c0   = quad * 64 + cl;

  const float* r = rois + k * 5;
  const int   b   = (int)r[0];
  const float x1s = r[1] * 0.25f;
  const float y1s = r[2] * 0.25f;
  const float x2s = r[3] * 0.25f;
  const float y2s = r[4] * 0.25f;
  const float roi_w = fmaxf(x2s - x1s, 1.0f);
  const float roi_h = fmaxf(y2s - y1s, 1.0f);
  const float bw = roi_w / 7.0f;
  const float bh = roi_h / 7.0f;

  // whole-roi validity (coords monotone: min at p=0,i=0; max at p=6,i=1)
  const bool valid = (y1s + 0.25f * bh >= -1.0f) && (y1s + 6.75f * bh <= (float)IN_H) &&
                     (x1s + 0.25f * bw >= -1.0f) && (x1s + 6.75f * bw <= (float)IN_W);
  const float scale = valid ? 0.25f : 0.0f;

  const ushort* base = nhwc + (size_t)b * PLANE * NCH + c0;

  for (int p = pg; p < OUT_HW; p += 32) {
    const int ph = p / 7;
    const int pw = p - ph * 7;
    const float ybase = y1s + bh * (float)ph;
    const float xbase = x1s + bw * (float)pw;

    float acc[8] = {0.f, 0.f, 0.f, 0.f, 0.f, 0.f, 0.f, 0.f};
#pragma unroll
    for (int iy = 0; iy < 2; ++iy) {
      const float y  = ybase + (bh * 0.5f) * ((float)iy + 0.5f);
      const float yc = fminf(fmaxf(y, 0.0f), (float)(IN_H - 1));
      const float ylf = floorf(yc);
      const int   yl  = (int)ylf;
      const int   yh  = min(yl + 1, IN_H - 1);
      const float ly  = yc - ylf;
      const float hy  = 1.0f - ly;
      const ushort* rowl = base + (size_t)yl * IN_W * NCH;
      const ushort* rowh = base + (size_t)yh * IN_W * NCH;
#pragma unroll
      for (int ix = 0; ix < 2; ++ix) {
        const float x  = xbase + (bw * 0.5f) * ((float)ix + 0.5f);
        const float xc = fminf(fmaxf(x, 0.0f), (float)(IN_W - 1));
        const float xlf = floorf(xc);
        const int   xl  = (int)xlf;
        const int   xh  = min(xl + 1, IN_W - 1);
        const float lx  = xc - xlf;
        const float hx  = 1.0f - lx;

        const uint4 q1 = *(const uint4*)(rowl + (size_t)xl * NCH);
        const uint4 q2 = *(const uint4*)(rowl + (size_t)xh * NCH);
        const uint4 q3 = *(const uint4*)(rowh + (size_t)xl * NCH);
        const uint4 q4 = *(const uint4*)(rowh + (size_t)xh * NCH);

        acc8(acc, q1, hy * hx);
        acc8(acc, q2, hy * lx);
        acc8(acc, q3, ly * hx);
        acc8(acc, q4, ly * lx);
      }
    }
#pragma unroll
    for (int j = 0; j < 8; ++j) sout[(cl + j) * OUT_HW + p] = acc[j] * scale;
  }
  __syncthreads();

  // contiguous coalesced write of this quarter-roi's (64,7,7) tile
  float4* o4 = (float4*)(out + ((size_t)k * NCH + quad * 64) * OUT_HW);
  const float4* s4 = (const float4*)sout;
  for (int m = t; m < (64 * OUT_HW) / 4; m += 256) o4[m] = s4[m];
}

// ---------------- fallback (ws too small): direct gather, f32 NCHW ----------------
__global__ __launch_bounds__(256) void roi_align_fallback(
    const float* __restrict__ input,
    const float* __restrict__ rois,
    float* __restrict__ out) {
  const int blk  = blockIdx.x;
  const int k    = blk >> 6;
  const int cg   = blk & 63;
  const int wave = threadIdx.x >> 6;
  const int lane = threadIdx.x & 63;
  const int c    = (cg << 2) + wave;

  const float* r = rois + k * 5;
  const int   b   = (int)r[0];
  const float x1s = r[1] * 0.25f;
  const float y1s = r[2] * 0.25f;
  const float roi_w = fmaxf(r[3] * 0.25f - x1s, 1.0f);
  const float roi_h = fmaxf(r[4] * 0.25f - y1s, 1.0f);
  const float bw = roi_w / 7.0f;
  const float bh = roi_h / 7.0f;
  const bool valid = (y1s + 0.25f * bh >= -1.0f) && (y1s + 6.75f * bh <= (float)IN_H) &&
                     (x1s + 0.25f * bw >= -1.0f) && (x1s + 6.75f * bw <= (float)IN_W);
  if (lane >= OUT_HW) return;
  const int ph = lane / 7;
  const int pw = lane - ph * 7;
  const float* plane = input + ((size_t)(b * NCH + c)) * PLANE;
  const float ybase = y1s + bh * (float)ph;
  const float xbase = x1s + bw * (float)pw;
  float acc = 0.0f;
#pragma unroll
  for (int iy = 0; iy < 2; ++iy) {
    const float y  = ybase + (bh * 0.5f) * ((float)iy + 0.5f);
    const float yc = fminf(fmaxf(y, 0.0f), (float)(IN_H - 1));
    const float ylf = floorf(yc);
    const int yl = (int)ylf;
    const int yh = min(yl + 1, IN_H - 1);
    const float ly = yc - ylf, hy = 1.0f - ly;
#pragma unroll
    for (int ix = 0; ix < 2; ++ix) {
      const float x  = xbase + (bw * 0.5f) * ((float)ix + 0.5f);
      const float xc = fminf(fmaxf(x, 0.0f), (float)(IN_W - 1));
      const float xlf = floorf(xc);
      const int xl = (int)xlf;
      const int xh = min(xl + 1, IN_W - 1);
      const float lx = xc - xlf, hx = 1.0f - lx;
      const float* row_l = plane + yl * IN_W;
      const float* row_h = plane + yh * IN_W;
      acc += hy * hx * row_l[xl] + hy * lx * row_l[xh] +
             ly * hx * row_h[xl] + ly * lx * row_h[xh];
    }
  }
  out[((size_t)k * NCH + c) * OUT_HW + lane] = valid ? acc * 0.25f : 0.0f;
}

extern "C" void kernel_launch(void* const* d_in, const int* in_sizes, int n_in,
                              void* d_out, int out_size, void* d_ws, size_t ws_size,
                              hipStream_t stream) {
  const float* input = (const float*)d_in[0];
  const float* rois  = (const float*)d_in[1];
  float* out = (float*)d_out;

  const size_t need = (size_t)2 * PLANE * NCH * sizeof(ushort);  // 40.96 MB
  if (ws_size >= need) {
    ushort* nhwc = (ushort*)d_ws;
    transpose_bf16_kernel<<<2 * 625, 256, 0, stream>>>(input, nhwc);
    roi_nhwc_bf16_kernel<<<NROI * 4, 256, 0, stream>>>(nhwc, rois, out);
  } else {
    roi_align_fallback<<<NROI * (NCH / 4), 256, 0, stream>>>(input, rois, out);
  }
}